// Round 1
// baseline (79.832 us; speedup 1.0000x reference)
//
#include <hip/hip_runtime.h>

#define NN 8
#define CC 16
#define HH 32
#define WW 32
#define OCH 64
#define OH 30
#define OW 30

// y[n,oc,p] = sum_i max(patch_i+5,1e-12)*exp(k[i,oc]+5) - dw*sum_i raw_i - dx*sum_i k[i,oc] + bias[oc]
__global__ __launch_bounds__(256) void bm_smax_kernel(
    const float* __restrict__ x, const float* __restrict__ kw_,
    const float* __restrict__ bias, const float* __restrict__ pdx,
    const float* __restrict__ pdw, float* __restrict__ out)
{
    __shared__ __align__(16) float sE[144 * OCH];   // exp(k+5), [i][oc]
    __shared__ float sA[3 * WW * 17];               // clamped input rows, [kh][w][c], c-stride padded to 17
    __shared__ float sKsum[OCH];
    __shared__ float sRaw[32];

    const int t = threadIdx.x;
    const int b = blockIdx.x;
    const int n = b / OH;
    const int y = b % OH;

    // ---- stage clamped input rows (coalesced global reads) ----
    for (int idx = t; idx < 3 * CC * WW; idx += 256) {
        int w    = idx & 31;
        int rest = idx >> 5;
        int c    = rest & 15;
        int kh   = rest >> 4;
        float v = x[((n * CC + c) * HH + (y + kh)) * WW + w];
        sA[(kh * WW + w) * 17 + c] = fmaxf(v + 5.0f, 1e-12f);
    }
    // ---- stage E = exp(k+5) ----
    for (int idx = t; idx < 144 * OCH; idx += 256) {
        sE[idx] = __expf(kw_[idx] + 5.0f);
    }
    // ---- k column sums (wave 0) / raw box sums (wave 1) ----
    if (t < 64) {
        float s = 0.f;
        for (int i = 0; i < 144; ++i) s += kw_[i * OCH + t];
        sKsum[t] = s * pdx[0];
    } else if (t < 96) {
        int xo = t - 64;
        float s = 0.f;
        if (xo < OW) {
            for (int kh = 0; kh < 3; ++kh)
                for (int c = 0; c < CC; ++c) {
                    const float* p = &x[((n * CC + c) * HH + (y + kh)) * WW + xo];
                    s += p[0] + p[1] + p[2];
                }
        }
        if (xo < 32) sRaw[xo] = s * pdw[0];
    }
    __syncthreads();

    // ---- main: lanes over xo (coalesced stores), 8 oc per thread ----
    const int xo  = t & 31;
    const int ocg = t >> 5;          // 0..7 -> oc = ocg*8 + j
    if (xo >= OW) return;

    float acc[8];
#pragma unroll
    for (int j = 0; j < 8; ++j) acc[j] = 0.f;

#pragma unroll
    for (int kh = 0; kh < 3; ++kh) {
#pragma unroll
        for (int kwi = 0; kwi < 3; ++kwi) {
            const int arow = (kh * WW + xo + kwi) * 17;
            const int erow = ((kh * 3 + kwi) * CC) * OCH + ocg * 8;
#pragma unroll
            for (int c = 0; c < CC; ++c) {
                float a = sA[arow + c];
                const float4 e0 = *(const float4*)&sE[erow + c * OCH];
                const float4 e1 = *(const float4*)&sE[erow + c * OCH + 4];
                acc[0] = fmaf(a, e0.x, acc[0]);
                acc[1] = fmaf(a, e0.y, acc[1]);
                acc[2] = fmaf(a, e0.z, acc[2]);
                acc[3] = fmaf(a, e0.w, acc[3]);
                acc[4] = fmaf(a, e1.x, acc[4]);
                acc[5] = fmaf(a, e1.y, acc[5]);
                acc[6] = fmaf(a, e1.z, acc[6]);
                acc[7] = fmaf(a, e1.w, acc[7]);
            }
        }
    }

    const float rsum = sRaw[xo];
#pragma unroll
    for (int j = 0; j < 8; ++j) {
        int oc = ocg * 8 + j;
        out[((n * OCH + oc) * OH + y) * OW + xo] = acc[j] - rsum - sKsum[oc] + bias[oc];
    }
}

extern "C" void kernel_launch(void* const* d_in, const int* in_sizes, int n_in,
                              void* d_out, int out_size, void* d_ws, size_t ws_size,
                              hipStream_t stream) {
    const float* x    = (const float*)d_in[0];
    const float* k    = (const float*)d_in[1];
    const float* bias = (const float*)d_in[2];
    const float* pdx  = (const float*)d_in[3];
    const float* pdw  = (const float*)d_in[4];
    float* out = (float*)d_out;

    bm_smax_kernel<<<NN * OH, 256, 0, stream>>>(x, k, bias, pdx, pdw, out);
}